// Round 7
// baseline (223.208 us; speedup 1.0000x reference)
//
#include <hip/hip_runtime.h>
#include <hip/hip_bf16.h>
#include <hip/hip_fp8.h>

// SNN forward, round 7: 4-phase-per-K-tile pipelined GEMM (m201 schedule).
// Per phase: {ds_reads + staged work; barrier; lgkmcnt(0); setprio MFMA x16
// setprio; barrier}. B staged via global_load_lds 1 tile ahead (counted
// vmcnt(8), never drained to 0 mid-loop); A reg-staged 2 tiles ahead with
// async-split (issue Ph3, cvt Ph2, ds_write Ph3). Tail tile barrier-free.

#define B_    256
#define T_    250
#define NIN   700
#define NHID  512
#define NOUT  20
#define NSTEP 11          // K-tiles of 64 (704 = 11*64, zero-padded)

typedef __attribute__((ext_vector_type(8))) short short8;
typedef __attribute__((ext_vector_type(4))) float f32x4;

static __device__ __forceinline__ ushort f2bf(float f) {
  union { float f; unsigned u; } v; v.f = f;
  unsigned r = (v.u + 0x7FFF + ((v.u >> 16) & 1)) >> 16;  // RNE
  return (ushort)r;
}
static __device__ __forceinline__ unsigned cvtpk_bf16(float a, float b) {
  unsigned r;
  asm("v_cvt_pk_bf16_f32 %0, %1, %2" : "=v"(r) : "v"(a), "v"(b));
  return r;
}
static __device__ __forceinline__ void gload_lds16(const void* g, void* l) {
  __builtin_amdgcn_global_load_lds(
      (const __attribute__((address_space(1))) unsigned*)g,
      (__attribute__((address_space(3))) unsigned*)l, 16, 0, 0);
}
// storage permutation within a 512-col row (self-inverse):
static __device__ __forceinline__ int hperm(int s) {
  return (s & 256) | ((s & 15) << 4) | ((s >> 4) & 15);
}

// ---------------- prep: w1 -> bf16 fragment slabs ----------------
// elem = ((nh*NSTEP+kt)<<14) + (k32<<13) + (cb<<9) + (lane<<3) + e
// col = nh*256 + cb*16 + (lane&15); k = kt*64 + k32*32 + (lane>>4)*8 + e
__global__ __launch_bounds__(256) void prep_kernel(
    const float* __restrict__ w1, ushort* __restrict__ w1frag) {
  int i = blockIdx.x * 256 + threadIdx.x;
  if (i >= 2 * NSTEP * 16384) return;
  int e    = i & 7;
  int lane = (i >> 3) & 63;
  int cb   = (i >> 9) & 15;
  int k32  = (i >> 13) & 1;
  int slab = i >> 14;
  int nh = slab / NSTEP, kt = slab - nh * NSTEP;
  int col = nh * 256 + cb * 16 + (lane & 15);
  int k   = kt * 64 + k32 * 32 + (lane >> 4) * 8 + e;
  w1frag[i] = (k < NIN) ? f2bf(w1[(size_t)col * NIN + k]) : (ushort)0;
}

// ---------------- MFMA GEMM ----------------
// grid = 512; block = 512 (8 waves, 2x4), tile 256 rows x 256 cols, BK=64.
__global__ __launch_bounds__(512, 2) void gemm_mfma(
    const float* __restrict__ x, const ushort* __restrict__ w1frag,
    const float* __restrict__ alpha, unsigned char* __restrict__ iff,
    int t0, int tcount) {
  __shared__ __align__(16) char Al[2][32768];
  __shared__ __align__(16) char Bl[2][32768];

  int p = blockIdx.x;
  int tl = ((p >> 4) << 3) | (p & 7);
  int nh = (p >> 3) & 1;
  if (tl >= tcount) return;
  int t = t0 + tl;

  int tid = threadIdx.x, lane = tid & 63, wave = tid >> 6;
  int wr = wave >> 2, wc = wave & 3;       // 2 x 4 wave grid
  int lm = lane & 15, lk = lane >> 4;

  int srow = tid >> 1;           // 0..255 (batch row)
  int so4  = (tid & 1) * 4;      // k-oct group 0 or 4
  const float* ap = x + ((size_t)srow * T_ + t) * NIN;

  f32x4 acc[8][4];
#pragma unroll
  for (int i = 0; i < 8; ++i)
#pragma unroll
    for (int j = 0; j < 4; ++j) acc[i][j] = (f32x4){0.f, 0.f, 0.f, 0.f};

  float4 sa[8];        // one A-stage tile in flight (32 VGPR)
  uint4  pk4[4];       // converted A tile (16 VGPR)
  short8 afv[4], bfv[4];

#define LOADA(KT) do { _Pragma("unroll")                                     \
  for (int q_ = 0; q_ < 4; ++q_) {                                           \
    int k0_ = (KT) * 64 + so4 * 8 + q_ * 8;                                  \
    sa[2*q_]   = (k0_ + 4 <= NIN) ? *(const float4*)(ap + k0_)               \
                                  : (float4){0.f,0.f,0.f,0.f};               \
    sa[2*q_+1] = (k0_ + 8 <= NIN) ? *(const float4*)(ap + k0_ + 4)           \
                                  : (float4){0.f,0.f,0.f,0.f};               \
  } } while (0)

#define CVTA() do { _Pragma("unroll")                                        \
  for (int q_ = 0; q_ < 4; ++q_) {                                           \
    pk4[q_].x = cvtpk_bf16(sa[2*q_].x,   sa[2*q_].y);                        \
    pk4[q_].y = cvtpk_bf16(sa[2*q_].z,   sa[2*q_].w);                        \
    pk4[q_].z = cvtpk_bf16(sa[2*q_+1].x, sa[2*q_+1].y);                      \
    pk4[q_].w = cvtpk_bf16(sa[2*q_+1].z, sa[2*q_+1].w);                      \
  } } while (0)

#define WRITEA(BUF) do { _Pragma("unroll")                                   \
  for (int q_ = 0; q_ < 4; ++q_) {                                           \
    int o_ = so4 + q_;                                                       \
    int byo_ = (((o_ >> 2) * 16 + (srow >> 4)) << 10)                        \
             + (((((o_ & 3) << 4) | (srow & 15))) << 4);                     \
    byo_ ^= ((srow >> 4) & 7) << 4;                                          \
    *(uint4*)(&Al[BUF][byo_]) = pk4[q_];                                     \
  } } while (0)

#define STAGEB(BUF, KT) do {                                                 \
    const char* gs_ = (const char*)w1frag                                    \
                    + (((size_t)(nh * NSTEP + (KT))) << 15);                 \
    _Pragma("unroll")                                                        \
    for (int i_ = 0; i_ < 4; ++i_) {                                         \
      int off_ = i_ * 8192 + wave * 1024;                                    \
      gload_lds16(gs_ + off_ + lane * 16, &Bl[BUF][off_]);                   \
    } } while (0)

#define DSREAD_BF(CUR, KH) do { _Pragma("unroll")                            \
  for (int j_ = 0; j_ < 4; ++j_)                                             \
    bfv[j_] = *(const short8*)(&Bl[CUR][(((KH)*16 + wc*4 + j_) << 10)        \
                                        + lane * 16]); } while (0)

#define DSREAD_AF(CUR, KH, IH) do { _Pragma("unroll")                        \
  for (int i_ = 0; i_ < 4; ++i_) {                                           \
    int rb_ = (IH) * 4 + i_;                                                 \
    afv[i_] = *(const short8*)(&Al[CUR][(((KH)*16 + wr*8 + rb_) << 10)       \
                                        + ((lane*16) ^ (rb_ << 4))]);        \
  } } while (0)

#define MFMA16(IH) do {                                                      \
    __builtin_amdgcn_s_setprio(1);                                           \
    _Pragma("unroll")                                                        \
    for (int i_ = 0; i_ < 4; ++i_)                                           \
      _Pragma("unroll")                                                      \
      for (int j_ = 0; j_ < 4; ++j_)                                         \
        acc[(IH)*4 + i_][j_] = __builtin_amdgcn_mfma_f32_16x16x32_bf16(      \
            afv[i_], bfv[j_], acc[(IH)*4 + i_][j_], 0, 0, 0);                \
    __builtin_amdgcn_s_setprio(0);                                           \
  } while (0)

#define FENCE_LGKM()                                                         \
    asm volatile("s_waitcnt lgkmcnt(0)" ::: "memory");                       \
    __builtin_amdgcn_sched_barrier(0)

#define TILE(CUR, NXT, KT) do {                                              \
    /* Ph0: bf(kh0)+af(kh0,i0-3); issue B(kt+1) */                           \
    DSREAD_BF(CUR, 0); DSREAD_AF(CUR, 0, 0);                                 \
    STAGEB(NXT, (KT) + 1);                                                   \
    __builtin_amdgcn_s_barrier();                                            \
    FENCE_LGKM();                                                            \
    MFMA16(0);                                                               \
    __builtin_amdgcn_s_barrier();                                            \
    /* Ph1: af(kh0,i4-7) */                                                  \
    DSREAD_AF(CUR, 0, 1);                                                    \
    __builtin_amdgcn_s_barrier();                                            \
    FENCE_LGKM();                                                            \
    MFMA16(1);                                                               \
    __builtin_amdgcn_s_barrier();                                            \
    /* Ph2: bf(kh1)+af(kh1,i0-3); cvt A(kt+1) (auto vmcnt(4)) */             \
    DSREAD_BF(CUR, 1); DSREAD_AF(CUR, 1, 0);                                 \
    CVTA();                                                                  \
    __builtin_amdgcn_s_barrier();                                            \
    FENCE_LGKM();                                                            \
    MFMA16(0);                                                               \
    __builtin_amdgcn_s_barrier();                                            \
    /* Ph3: af(kh1,i4-7); write A(kt+1); issue A(kt+2); counted drain */     \
    DSREAD_AF(CUR, 1, 1);                                                    \
    WRITEA(NXT);                                                             \
    if ((KT) + 2 < NSTEP) {                                                  \
      LOADA((KT) + 2);                                                       \
      asm volatile("s_waitcnt vmcnt(8) lgkmcnt(0)" ::: "memory");            \
    } else {                                                                 \
      asm volatile("s_waitcnt vmcnt(0) lgkmcnt(0)" ::: "memory");            \
    }                                                                        \
    __builtin_amdgcn_sched_barrier(0);                                       \
    __builtin_amdgcn_s_barrier();                                            \
    __builtin_amdgcn_sched_barrier(0);                                       \
    MFMA16(1);                                                               \
    __builtin_amdgcn_s_barrier();                                            \
  } while (0)

  // prologue: tile0 A+B staged; A(1) issued; B(0) drained (vmcnt(8) leaves A(1))
  LOADA(0);
  STAGEB(0, 0);
  CVTA();            // compiler waits the 8 A(0) loads (vmcnt(4))
  WRITEA(0);
  LOADA(1);
  asm volatile("s_waitcnt vmcnt(8) lgkmcnt(0)" ::: "memory");
  __builtin_amdgcn_s_barrier();
  __builtin_amdgcn_sched_barrier(0);

  // tiles 0..9 (static buffer parity)
  for (int kt2 = 0; kt2 < NSTEP - 1; kt2 += 2) {
    TILE(0, 1, kt2);
    TILE(1, 0, kt2 + 1);
  }
  // tail tile 10 (buf0), no staging, compiler-managed waits, no barriers
#pragma unroll
  for (int kh = 0; kh < 2; ++kh) {
    DSREAD_BF(0, kh);
#pragma unroll
    for (int ih = 0; ih < 2; ++ih) {
      DSREAD_AF(0, kh, ih);
      MFMA16(ih);
    }
  }
#undef LOADA
#undef CVTA
#undef WRITEA
#undef STAGEB
#undef DSREAD_BF
#undef DSREAD_AF
#undef MFMA16
#undef FENCE_LGKM
#undef TILE

  // epilogue: scale by (1-alpha[col]); pack 4 fp8 -> one u32 at permuted pos
  float scl[4];
#pragma unroll
  for (int j = 0; j < 4; ++j)
    scl[j] = 1.0f - alpha[nh * 256 + wc * 64 + j * 16 + lm];
#pragma unroll
  for (int i = 0; i < 8; ++i) {
#pragma unroll
    for (int r = 0; r < 4; ++r) {
      int row = wr * 128 + i * 16 + lk * 4 + r;   // batch index b
      unsigned u = 0;
#pragma unroll
      for (int j = 0; j < 4; ++j) {
        __hip_fp8_e4m3 q(acc[i][j][r] * scl[j]);
        u |= ((unsigned)q.__x) << (8 * j);
      }
      *(unsigned*)(iff + ((size_t)(tl * 256 + row)) * NHID
                   + nh * 256 + lm * 16 + wc * 4) = u;
    }
  }
}

// ---------------- fused recurrence (unchanged from R6) ----------------
__global__ __launch_bounds__(64) void snn_recur(
    const unsigned char* __restrict__ iff, const float* __restrict__ wrec,
    const float* __restrict__ wout,
    const float* __restrict__ alpha, const float* __restrict__ rho,
    const float* __restrict__ beta_a, const float* __restrict__ beta_out,
    float* __restrict__ state, int* __restrict__ flags,
    float* __restrict__ dout, int Tc, int first, int last) {
  int lane = threadIdx.x;
  int b = blockIdx.x;
  int hbase = lane * 8;

  float* v1s = state;
  float* a1s = state + B_ * NHID;
  float* sps = state + 2 * B_ * NHID;
  float* vos = state + 3 * B_ * NHID;
  float* oss = vos + B_ * NOUT;

  int hact[8];
#pragma unroll
  for (int r = 0; r < 8; ++r) hact[r] = hperm(hbase + r);

  float v1[8], a1[8], sp[8], al[8], rh[8], ba[8];
#pragma unroll
  for (int r = 0; r < 8; ++r) {
    int h = hact[r];
    al[r] = alpha[h]; rh[r] = rho[h]; ba[r] = beta_a[h];
    if (first) { v1[r] = 0.f; a1[r] = 0.f; sp[r] = 0.f; }
    else {
      v1[r] = v1s[(size_t)b * NHID + hbase + r];
      a1[r] = a1s[(size_t)b * NHID + hbase + r];
      sp[r] = sps[(size_t)b * NHID + hbase + r];
    }
  }
  float vout = 0.f, osum = 0.f, bo = 0.f;
  if (lane < NOUT) {
    bo = beta_out[lane];
    if (!first) { vout = vos[b * NOUT + lane]; osum = oss[b * NOUT + lane]; }
  }

  int mode = first ? 0 : flags[b];
  int tle = 0;

  if (mode == 0) {
    uint2 pf[8];
#pragma unroll
    for (int j = 0; j < 8; ++j) {
      int tl = (j < Tc) ? j : (Tc - 1);
      pf[j] = *(const uint2*)(iff + ((size_t)tl * B_ + b) * NHID + hbase);
    }
    bool esc = false;
    for (int tb = 0; tb < Tc && !esc; tb += 8) {
#pragma unroll
      for (int j = 0; j < 8; ++j) {
        int tl = tb + j;
        if (!esc && tl < Tc) {
          float tv[8];
#pragma unroll
          for (int r = 0; r < 8; ++r) {
            unsigned w = (r < 4) ? pf[j].x : pf[j].y;
            __hip_fp8_e4m3 q; q.__x = (unsigned char)((w >> ((r & 3) * 8)) & 255u);
            tv[r] = al[r] * v1[r] + (float)q;   // iff pre-scaled by (1-alpha)
          }
          float m01 = fmaxf(tv[0], tv[1]), m23 = fmaxf(tv[2], tv[3]);
          float m45 = fmaxf(tv[4], tv[5]), m67 = fmaxf(tv[6], tv[7]);
          float mx = fmaxf(fmaxf(m01, m23), fmaxf(m45, m67));
          if (__ballot(mx > 1.0f)) {
            esc = true; tle = tl;
          } else {
#pragma unroll
            for (int r = 0; r < 8; ++r) v1[r] = tv[r];
            int nt = (tl + 8 < Tc) ? (tl + 8) : (Tc - 1);
            pf[j] = *(const uint2*)(iff + ((size_t)nt * B_ + b) * NHID + hbase);
          }
        }
      }
    }
    if (!esc) tle = Tc;
    mode = esc ? 1 : 0;
  }

  unsigned long long mask[8];
#pragma unroll
  for (int r = 0; r < 8; ++r) mask[r] = __ballot(sp[r] != 0.f);

  for (int tl = tle; tl < Tc; ++tl) {
    uint2 w2 = *(const uint2*)(iff + ((size_t)tl * B_ + b) * NHID + hbase);
    float iv[8];
#pragma unroll
    for (int r = 0; r < 8; ++r) {
      unsigned w = (r < 4) ? w2.x : w2.y;
      __hip_fp8_e4m3 q; q.__x = (unsigned char)((w >> ((r & 3) * 8)) & 255u);
      iv[r] = (float)q;
    }
    unsigned long long anyp = mask[0] | mask[1] | mask[2] | mask[3] |
                              mask[4] | mask[5] | mask[6] | mask[7];
    if (anyp) {
      float rec[8] = {0.f,0.f,0.f,0.f,0.f,0.f,0.f,0.f};
#pragma unroll
      for (int r2 = 0; r2 < 8; ++r2) {
        unsigned long long mm = mask[r2];
        while (mm) {
          int l2 = __ffsll(mm) - 1; mm &= (mm - 1);
          int hp = hperm(l2 * 8 + r2);
#pragma unroll
          for (int r = 0; r < 8; ++r)
            rec[r] += wrec[(size_t)hact[r] * NHID + hp];
        }
      }
#pragma unroll
      for (int r = 0; r < 8; ++r) iv[r] += (1.0f - al[r]) * rec[r];
    }

    float s[8];
#pragma unroll
    for (int r = 0; r < 8; ++r) {
      a1[r] = rh[r] * a1[r] + ba[r] * sp[r];
      v1[r] = al[r] * v1[r] + iv[r] - a1[r];
      s[r] = (v1[r] - 1.0f > 0.0f) ? 1.0f : 0.0f;
      v1[r] -= s[r];
      sp[r] = s[r];
      mask[r] = __ballot(s[r] != 0.f);
    }

    unsigned long long anyc = mask[0] | mask[1] | mask[2] | mask[3] |
                              mask[4] | mask[5] | mask[6] | mask[7];
    if (lane < NOUT) {
      float io = 0.f;
      if (anyc) {
#pragma unroll
        for (int r2 = 0; r2 < 8; ++r2) {
          unsigned long long mm = mask[r2];
          while (mm) {
            int l2 = __ffsll(mm) - 1; mm &= (mm - 1);
            int hp = hperm(l2 * 8 + r2);
            io += wout[(size_t)lane * NHID + hp];
          }
        }
      }
      vout = bo * vout + (1.0f - bo) * io;
      float so = (vout - 1.0f > 0.0f) ? 1.0f : 0.0f;
      vout -= so;
      osum += vout;
    }
  }

  if (last) {
    if (lane < NOUT) dout[b * NOUT + lane] = osum / (float)T_;
  } else {
#pragma unroll
    for (int r = 0; r < 8; ++r) {
      v1s[(size_t)b * NHID + hbase + r] = v1[r];
      a1s[(size_t)b * NHID + hbase + r] = a1[r];
      sps[(size_t)b * NHID + hbase + r] = sp[r];
    }
    if (lane < NOUT) { vos[b * NOUT + lane] = vout; oss[b * NOUT + lane] = osum; }
    if (lane == 0) flags[b] = mode;
  }
}

extern "C" void kernel_launch(void* const* d_in, const int* in_sizes, int n_in,
                              void* d_out, int out_size, void* d_ws, size_t ws_size,
                              hipStream_t stream) {
  const float* x      = (const float*)d_in[0];
  const float* w1     = (const float*)d_in[1];
  const float* wrec   = (const float*)d_in[2];
  const float* wout   = (const float*)d_in[3];
  const float* alpha  = (const float*)d_in[4];
  const float* rho    = (const float*)d_in[5];
  const float* beta_a = (const float*)d_in[6];
  const float* bout   = (const float*)d_in[7];
  float* out = (float*)d_out;

  char* ws = (char*)d_ws;
  const size_t w1frag_bytes = (size_t)2 * NSTEP * 16384 * 2;                 // 704 KB
  const size_t state_off = w1frag_bytes;
  const size_t state_bytes = (size_t)(3 * B_ * NHID + 2 * B_ * NOUT) * 4;
  const size_t flags_off = state_off + state_bytes;
  const size_t iff_off   = flags_off + B_ * 4;

  ushort* w1frag = (ushort*)(ws);
  float*  statep = (float*)(ws + state_off);
  int*    flagsp = (int*)(ws + flags_off);
  unsigned char* iff = (unsigned char*)(ws + iff_off);

  const size_t per_step = (size_t)B_ * NHID;  // 128 KB per timestep (fp8)
  long long avail = (long long)ws_size - (long long)iff_off;
  int Tc = (int)(avail / (long long)per_step);
  if (Tc > T_) Tc = T_;
  if (Tc < 1) Tc = 1;

  prep_kernel<<<dim3((2 * NSTEP * 16384 + 255) / 256), dim3(256), 0, stream>>>(
      w1, w1frag);

  for (int t0 = 0; t0 < T_; t0 += Tc) {
    int tc = (T_ - t0 < Tc) ? (T_ - t0) : Tc;
    gemm_mfma<<<dim3(512), dim3(512), 0, stream>>>(x, w1frag, alpha, iff, t0, tc);
    snn_recur<<<dim3(B_), dim3(64), 0, stream>>>(
        iff, wrec, wout, alpha, rho, beta_a, bout, statep, flagsp, out,
        tc, (t0 == 0) ? 1 : 0, (t0 + tc >= T_) ? 1 : 0);
  }
}

// Round 8
// 114.843 us; speedup vs baseline: 1.9436x; 1.9436x over previous
//
#include <hip/hip_runtime.h>
#include <hip/hip_bf16.h>
#include <hip/hip_fp8.h>

// SNN forward, round 8: time-major tiling so x streams sequentially.
//   Block = (b, t-half, n-half): A-slab x[b][t0:t0+125][:] contiguous 350KB.
//   Tile 128(t) x 256(h), BK=32, 8 waves (2x4), wave 64x64, acc=64 VGPR,
//   2 blocks/CU. A: reg-staged f32->bf16, k-octet-major LDS (conflict-free).
//   B: fragment-ordered slabs via global_load_lds, counted vmcnt. iff [b][t][h]
//   fp8 pre-scaled by (1-alpha), permuted within 64-col chunks (u32 stores).

#define B_    256
#define T_    250
#define NIN   700
#define NHID  512
#define NOUT  20
#define NKT   22          // K-tiles of 32 (704 = 22*32, zero-padded)

typedef __attribute__((ext_vector_type(8))) short short8;
typedef __attribute__((ext_vector_type(4))) float f32x4;

static __device__ __forceinline__ ushort f2bf(float f) {
  union { float f; unsigned u; } v; v.f = f;
  unsigned r = (v.u + 0x7FFF + ((v.u >> 16) & 1)) >> 16;  // RNE
  return (ushort)r;
}
static __device__ __forceinline__ unsigned cvtpk_bf16(float a, float b) {
  unsigned r;
  asm("v_cvt_pk_bf16_f32 %0, %1, %2" : "=v"(r) : "v"(a), "v"(b));
  return r;
}
static __device__ __forceinline__ void gload_lds16(const void* g, void* l) {
  __builtin_amdgcn_global_load_lds(
      (const __attribute__((address_space(1))) unsigned*)g,
      (__attribute__((address_space(3))) unsigned*)l, 16, 0, 0);
}
// storage slot s (0..511) -> actual hidden unit h (within-64 inner permutation)
static __device__ __forceinline__ int hstoremap(int s) {
  return (s & 0x1C0) | ((s & 3) << 4) | ((s >> 2) & 15);
}

// ---------------- prep: w1 -> bf16 fragment slabs ----------------
// slab = nh*NKT + kt (16KB each); elem i: e=i&7, lane=(i>>3)&63, cb=(i>>9)&15
// col = nh*256 + cb*16 + (lane&15); k = kt*32 + (lane>>4)*8 + e
__global__ __launch_bounds__(256) void prep_kernel(
    const float* __restrict__ w1, ushort* __restrict__ w1frag) {
  int i = blockIdx.x * 256 + threadIdx.x;
  if (i >= 2 * NKT * 8192) return;
  int e    = i & 7;
  int lane = (i >> 3) & 63;
  int cb   = (i >> 9) & 15;
  int slab = i >> 13;
  int nh = slab / NKT, kt = slab - nh * NKT;
  int col = nh * 256 + cb * 16 + (lane & 15);
  int k   = kt * 32 + (lane >> 4) * 8 + e;
  w1frag[i] = (k < NIN) ? f2bf(w1[(size_t)col * NIN + k]) : (ushort)0;
}

// ---------------- MFMA GEMM ----------------
// grid = 1024: p -> b=p>>2, th=(p>>1)&1, nh=p&1. block 512 thr / 8 waves (2x4).
__global__ __launch_bounds__(512, 4) void gemm_mfma(
    const float* __restrict__ x, const ushort* __restrict__ w1frag,
    const float* __restrict__ alpha, unsigned char* __restrict__ iff,
    int t0, int tc) {
  __shared__ __align__(16) char Al[2][8192];    // [octet 0..3][row 0..127][16B]
  __shared__ __align__(16) char Bl[2][16384];   // [cb 0..15][lane 0..63][16B]

  int p = blockIdx.x;
  int b  = p >> 2;
  int th = (p >> 1) & 1;
  int nh = p & 1;
  int rows0 = (tc + 1) >> 1;
  int t0b = th * rows0;
  int rv = tc - t0b; if (rv > rows0) rv = rows0; if (rv < 0) rv = 0;

  int tid = threadIdx.x, lane = tid & 63, wave = tid >> 6;
  int wr = wave >> 2, wc = wave & 3;       // 2 x 4 wave grid (64x64 each)
  int lm = lane & 15, lk = lane >> 4;

  int srow = tid >> 2;           // 0..127 (t-offset within tile)
  int kq   = tid & 3;            // k-octet 0..3 (8 f32 at k = kt*32 + kq*8)
  int tg   = t0 + t0b + srow;    // global t
  const float* ap = x + ((size_t)b * T_ + tg) * NIN;
  bool rowok = (tg < T_) && (srow < 128);

  f32x4 acc[4][4];
#pragma unroll
  for (int i = 0; i < 4; ++i)
#pragma unroll
    for (int j = 0; j < 4; ++j) acc[i][j] = (f32x4){0.f, 0.f, 0.f, 0.f};

  float4 s0, s1;       // one A-stage pair (8 VGPR)
  uint4  pk;           // converted (4 VGPR)

#define LOADA(KT) do {                                                       \
    int k0_ = (KT) * 32 + kq * 8;                                            \
    s0 = (rowok && k0_ + 4 <= NIN) ? *(const float4*)(ap + k0_)              \
                                   : (float4){0.f,0.f,0.f,0.f};              \
    s1 = (rowok && k0_ + 8 <= NIN) ? *(const float4*)(ap + k0_ + 4)          \
                                   : (float4){0.f,0.f,0.f,0.f};              \
  } while (0)

#define CVTA() do {                                                          \
    pk.x = cvtpk_bf16(s0.x, s0.y); pk.y = cvtpk_bf16(s0.z, s0.w);            \
    pk.z = cvtpk_bf16(s1.x, s1.y); pk.w = cvtpk_bf16(s1.z, s1.w);            \
  } while (0)

#define WRITEA(BUF) do {                                                     \
    *(uint4*)(&Al[BUF][kq * 2048 + srow * 16]) = pk;                         \
  } while (0)

#define STAGEB(BUF, KT) do {                                                 \
    const char* gs_ = (const char*)w1frag                                    \
                    + (((size_t)(nh * NKT + (KT))) << 14);                   \
    _Pragma("unroll")                                                        \
    for (int i_ = 0; i_ < 2; ++i_) {                                         \
      int off_ = i_ * 8192 + wave * 1024;                                    \
      gload_lds16(gs_ + off_ + lane * 16, &Bl[BUF][off_]);                   \
    } } while (0)

  // prologue
  LOADA(0);
  STAGEB(0, 0);
  CVTA();                      // compiler waits A(0)'s 2 loads
  WRITEA(0);
  LOADA(1);                    // 2 loads in flight
  asm volatile("s_waitcnt vmcnt(2) lgkmcnt(0)" ::: "memory");  // B(0) done
  __builtin_amdgcn_s_barrier();
  __builtin_amdgcn_sched_barrier(0);

#pragma unroll 2
  for (int kt = 0; kt < NKT; ++kt) {
    const int cur = kt & 1, nxt = cur ^ 1;
    if (kt + 1 < NKT) STAGEB(nxt, kt + 1);   // 2 gload, stay in flight
    short8 af[4], bf[4];
#pragma unroll
    for (int i = 0; i < 4; ++i)
      af[i] = *(const short8*)(&Al[cur][lk * 2048 + (wr * 64 + i * 16 + lm) * 16]);
#pragma unroll
    for (int j = 0; j < 4; ++j)
      bf[j] = *(const short8*)(&Bl[cur][(wc * 4 + j) * 1024 + lane * 16]);
    __builtin_amdgcn_s_setprio(1);
#pragma unroll
    for (int i = 0; i < 4; ++i)
#pragma unroll
      for (int j = 0; j < 4; ++j)
        acc[i][j] = __builtin_amdgcn_mfma_f32_16x16x32_bf16(
            af[i], bf[j], acc[i][j], 0, 0, 0);
    __builtin_amdgcn_s_setprio(0);
    if (kt + 1 < NKT) {
      CVTA();                                // waits A(kt+1), leaves B(kt+1)
      WRITEA(nxt);
      if (kt + 2 < NKT) {
        LOADA(kt + 2);                       // 2 loads stay in flight
        asm volatile("s_waitcnt vmcnt(2) lgkmcnt(0)" ::: "memory");
      } else {
        asm volatile("s_waitcnt vmcnt(0) lgkmcnt(0)" ::: "memory");
      }
      __builtin_amdgcn_s_barrier();
      __builtin_amdgcn_sched_barrier(0);
    }
  }
#undef LOADA
#undef CVTA
#undef WRITEA
#undef STAGEB

  // epilogue: scale by (1-alpha[col]); pack 4 fp8 (j=0..3) into one u32 at
  // permuted slot s0 = nh*256 + wc*64 + lm*4  (byte j <-> col j*16+lm).
  float scl[4];
#pragma unroll
  for (int j = 0; j < 4; ++j)
    scl[j] = 1.0f - alpha[nh * 256 + wc * 64 + j * 16 + lm];
#pragma unroll
  for (int i = 0; i < 4; ++i) {
#pragma unroll
    for (int r = 0; r < 4; ++r) {
      int row = wr * 64 + i * 16 + lk * 4 + r;   // t-offset within tile
      if (row < rv) {
        unsigned u = 0;
#pragma unroll
        for (int j = 0; j < 4; ++j) {
          __hip_fp8_e4m3 q(acc[i][j][r] * scl[j]);
          u |= ((unsigned)q.__x) << (8 * j);
        }
        *(unsigned*)(iff + ((size_t)b * tc + t0b + row) * NHID
                     + nh * 256 + wc * 64 + lm * 4) = u;
      }
    }
  }
}

// ---------------- fused recurrence ----------------
// 256 blocks x 64 threads; block b = batch row; iff [b][t][h] fp8 pre-scaled.
// Lane owns storage slots [lane*8, lane*8+8); actual h = hstoremap(slot).
__global__ __launch_bounds__(64) void snn_recur(
    const unsigned char* __restrict__ iff, const float* __restrict__ wrec,
    const float* __restrict__ wout,
    const float* __restrict__ alpha, const float* __restrict__ rho,
    const float* __restrict__ beta_a, const float* __restrict__ beta_out,
    float* __restrict__ state, int* __restrict__ flags,
    float* __restrict__ dout, int Tc, int first, int last) {
  int lane = threadIdx.x;
  int b = blockIdx.x;
  int hbase = lane * 8;
  const unsigned char* ib = iff + (size_t)b * Tc * NHID + hbase;

  float* v1s = state;
  float* a1s = state + B_ * NHID;
  float* sps = state + 2 * B_ * NHID;
  float* vos = state + 3 * B_ * NHID;
  float* oss = vos + B_ * NOUT;

  int hact[8];
#pragma unroll
  for (int r = 0; r < 8; ++r) hact[r] = hstoremap(hbase + r);

  float v1[8], a1[8], sp[8], al[8], rh[8], ba[8];
#pragma unroll
  for (int r = 0; r < 8; ++r) {
    int h = hact[r];
    al[r] = alpha[h]; rh[r] = rho[h]; ba[r] = beta_a[h];
    if (first) { v1[r] = 0.f; a1[r] = 0.f; sp[r] = 0.f; }
    else {
      v1[r] = v1s[(size_t)b * NHID + hbase + r];
      a1[r] = a1s[(size_t)b * NHID + hbase + r];
      sp[r] = sps[(size_t)b * NHID + hbase + r];
    }
  }
  float vout = 0.f, osum = 0.f, bo = 0.f;
  if (lane < NOUT) {
    bo = beta_out[lane];
    if (!first) { vout = vos[b * NOUT + lane]; osum = oss[b * NOUT + lane]; }
  }

  int mode = first ? 0 : flags[b];
  int tle = 0;

  if (mode == 0) {
    // fast path: no spike has ever fired
    uint2 pf[8];
#pragma unroll
    for (int j = 0; j < 8; ++j) {
      int tl = (j < Tc) ? j : (Tc - 1);
      pf[j] = *(const uint2*)(ib + (size_t)tl * NHID);
    }
    bool esc = false;
    for (int tb = 0; tb < Tc && !esc; tb += 8) {
#pragma unroll
      for (int j = 0; j < 8; ++j) {
        int tl = tb + j;
        if (!esc && tl < Tc) {
          float tv[8];
#pragma unroll
          for (int r = 0; r < 8; ++r) {
            unsigned w = (r < 4) ? pf[j].x : pf[j].y;
            __hip_fp8_e4m3 q; q.__x = (unsigned char)((w >> ((r & 3) * 8)) & 255u);
            tv[r] = al[r] * v1[r] + (float)q;   // iff pre-scaled by (1-alpha)
          }
          float m01 = fmaxf(tv[0], tv[1]), m23 = fmaxf(tv[2], tv[3]);
          float m45 = fmaxf(tv[4], tv[5]), m67 = fmaxf(tv[6], tv[7]);
          float mx = fmaxf(fmaxf(m01, m23), fmaxf(m45, m67));
          if (__ballot(mx > 1.0f)) {
            esc = true; tle = tl;
          } else {
#pragma unroll
            for (int r = 0; r < 8; ++r) v1[r] = tv[r];
            int nt = (tl + 8 < Tc) ? (tl + 8) : (Tc - 1);
            pf[j] = *(const uint2*)(ib + (size_t)nt * NHID);
          }
        }
      }
    }
    if (!esc) tle = Tc;
    mode = esc ? 1 : 0;
  }

  // full path (fallback / post-first-spike)
  unsigned long long mask[8];
#pragma unroll
  for (int r = 0; r < 8; ++r) mask[r] = __ballot(sp[r] != 0.f);

  for (int tl = tle; tl < Tc; ++tl) {
    uint2 w2 = *(const uint2*)(ib + (size_t)tl * NHID);
    float iv[8];
#pragma unroll
    for (int r = 0; r < 8; ++r) {
      unsigned w = (r < 4) ? w2.x : w2.y;
      __hip_fp8_e4m3 q; q.__x = (unsigned char)((w >> ((r & 3) * 8)) & 255u);
      iv[r] = (float)q;   // = (1-alpha)*i_ff
    }
    unsigned long long anyp = mask[0] | mask[1] | mask[2] | mask[3] |
                              mask[4] | mask[5] | mask[6] | mask[7];
    if (anyp) {
      float rec[8] = {0.f,0.f,0.f,0.f,0.f,0.f,0.f,0.f};
#pragma unroll
      for (int r2 = 0; r2 < 8; ++r2) {
        unsigned long long mm = mask[r2];
        while (mm) {
          int l2 = __ffsll(mm) - 1; mm &= (mm - 1);
          int hp = hstoremap(l2 * 8 + r2);
#pragma unroll
          for (int r = 0; r < 8; ++r)
            rec[r] += wrec[(size_t)hact[r] * NHID + hp];
        }
      }
#pragma unroll
      for (int r = 0; r < 8; ++r) iv[r] += (1.0f - al[r]) * rec[r];
    }

    float s[8];
#pragma unroll
    for (int r = 0; r < 8; ++r) {
      a1[r] = rh[r] * a1[r] + ba[r] * sp[r];
      v1[r] = al[r] * v1[r] + iv[r] - a1[r];
      s[r] = (v1[r] - 1.0f > 0.0f) ? 1.0f : 0.0f;
      v1[r] -= s[r];
      sp[r] = s[r];
      mask[r] = __ballot(s[r] != 0.f);
    }

    unsigned long long anyc = mask[0] | mask[1] | mask[2] | mask[3] |
                              mask[4] | mask[5] | mask[6] | mask[7];
    if (lane < NOUT) {
      float io = 0.f;
      if (anyc) {
#pragma unroll
        for (int r2 = 0; r2 < 8; ++r2) {
          unsigned long long mm = mask[r2];
          while (mm) {
            int l2 = __ffsll(mm) - 1; mm &= (mm - 1);
            int hp = hstoremap(l2 * 8 + r2);
            io += wout[(size_t)lane * NHID + hp];
          }
        }
      }
      vout = bo * vout + (1.0f - bo) * io;
      float so = (vout - 1.0f > 0.0f) ? 1.0f : 0.0f;
      vout -= so;
      osum += vout;
    }
  }

  if (last) {
    if (lane < NOUT) dout[b * NOUT + lane] = osum / (float)T_;
  } else {
#pragma unroll
    for (int r = 0; r < 8; ++r) {
      v1s[(size_t)b * NHID + hbase + r] = v1[r];
      a1s[(size_t)b * NHID + hbase + r] = a1[r];
      sps[(size_t)b * NHID + hbase + r] = sp[r];
    }
    if (lane < NOUT) { vos[b * NOUT + lane] = vout; oss[b * NOUT + lane] = osum; }
    if (lane == 0) flags[b] = mode;
  }
}

extern "C" void kernel_launch(void* const* d_in, const int* in_sizes, int n_in,
                              void* d_out, int out_size, void* d_ws, size_t ws_size,
                              hipStream_t stream) {
  const float* x      = (const float*)d_in[0];
  const float* w1     = (const float*)d_in[1];
  const float* wrec   = (const float*)d_in[2];
  const float* wout   = (const float*)d_in[3];
  const float* alpha  = (const float*)d_in[4];
  const float* rho    = (const float*)d_in[5];
  const float* beta_a = (const float*)d_in[6];
  const float* bout   = (const float*)d_in[7];
  float* out = (float*)d_out;

  char* ws = (char*)d_ws;
  const size_t w1frag_bytes = (size_t)2 * NKT * 8192 * 2;                    // 704 KB
  const size_t state_off = w1frag_bytes;
  const size_t state_bytes = (size_t)(3 * B_ * NHID + 2 * B_ * NOUT) * 4;
  const size_t flags_off = state_off + state_bytes;
  const size_t iff_off   = flags_off + B_ * 4;

  ushort* w1frag = (ushort*)(ws);
  float*  statep = (float*)(ws + state_off);
  int*    flagsp = (int*)(ws + flags_off);
  unsigned char* iff = (unsigned char*)(ws + iff_off);

  const size_t per_step = (size_t)B_ * NHID;  // 128 KB per timestep (fp8)
  long long avail = (long long)ws_size - (long long)iff_off;
  int Tc = (int)(avail / (long long)per_step);
  if (Tc > T_) Tc = T_;
  if (Tc < 1) Tc = 1;

  prep_kernel<<<dim3((2 * NKT * 8192 + 255) / 256), dim3(256), 0, stream>>>(
      w1, w1frag);

  for (int t0 = 0; t0 < T_; t0 += Tc) {
    int tc = (T_ - t0 < Tc) ? (T_ - t0) : Tc;
    gemm_mfma<<<dim3(B_ * 4), dim3(512), 0, stream>>>(
        x, w1frag, alpha, iff, t0, tc);
    snn_recur<<<dim3(B_), dim3(64), 0, stream>>>(
        iff, wrec, wout, alpha, rho, beta_a, bout, statep, flagsp, out,
        tc, (t0 == 0) ? 1 : 0, (t0 + tc >= T_) ? 1 : 0);
  }
}